// Round 2
// baseline (112.802 us; speedup 1.0000x reference)
//
#include <hip/hip_runtime.h>
#include <hip/hip_bf16.h>

typedef __attribute__((ext_vector_type(8))) short short8;
typedef __attribute__((ext_vector_type(4))) float f32x4;

static constexpr int S_ = 256;
static constexpr int D_ = 64;
static constexpr int QB = 4;
// softmax scale * log2(e): GEMM directly produces log2-domain scores
static constexpr float QSCALE = 0.125f * 1.44269504088896340736f;

__device__ __forceinline__ float bf2f(short b) {
    union { unsigned int u; float f; } x;
    x.u = ((unsigned int)(unsigned short)b) << 16;
    return x.f;
}
__device__ __forceinline__ unsigned short f2bf(float f) {
    union { float f; unsigned int u; } x; x.f = f;
    unsigned int u = x.u + 0x7fffu + ((x.u >> 16) & 1u);   // RNE
    return (unsigned short)(u >> 16);
}

__global__ __launch_bounds__(512, 4) void tritt_fused(
    const float* __restrict__ qg, const float* __restrict__ k1g,
    const float* __restrict__ k2g, const float* __restrict__ v1g,
    const float* __restrict__ v2g, float* __restrict__ outg)
{
    __shared__ unsigned short sK1[S_ * D_];   // bf16, XOR-swizzled rows (32 KB)
    __shared__ unsigned short sK2[S_ * D_];   // 32 KB
    __shared__ float sQ[QB * D_];             // pre-scaled Q (1 KB)
    __shared__ float sPi[QB][S_];             // 4 KB
    __shared__ float sPj[QB][S_];             // 4 KB
    __shared__ float sTmp[4][S_];             // 4 KB: pj partials, then O partials

    const int tid = threadIdx.x;
    const int h  = blockIdx.x >> 6;
    const int q0 = (blockIdx.x & 63) * QB;

    const float* K1h = k1g + h * (S_ * D_);
    const float* K2h = k2g + h * (S_ * D_);

    // ---- stage K1,K2 as swizzled bf16 ----
    #pragma unroll
    for (int it = 0; it < 8; ++it) {
        const int e4  = tid * 4 + it * 2048;
        const int row = e4 >> 6, d = e4 & 63;
        const int idx = row * 64 + (d ^ ((row & 7) << 3));
        const float4 a = *(const float4*)(K1h + e4);
        sK1[idx]   = f2bf(a.x); sK1[idx+1] = f2bf(a.y);
        sK1[idx+2] = f2bf(a.z); sK1[idx+3] = f2bf(a.w);
        const float4 b = *(const float4*)(K2h + e4);
        sK2[idx]   = f2bf(b.x); sK2[idx+1] = f2bf(b.y);
        sK2[idx+2] = f2bf(b.z); sK2[idx+3] = f2bf(b.w);
    }
    if (tid < 256)
        sQ[tid] = qg[(h * S_ + q0 + (tid >> 6)) * D_ + (tid & 63)] * QSCALE;
    __syncthreads();

    const int w   = tid >> 6;   // wave id -> i-strip [w*32, w*32+32)
    const int l   = tid & 63;
    const int g   = l >> 4;     // 16-lane group (holds k-slice g*8..g*8+7)
    const int sub = l & 15;

    for (int qq = 0; qq < QB; ++qq) {
        // ---- A fragments: W[i,d] = K1[i,d] * Qs[d], bf16, in registers ----
        float qs[2][8];
        #pragma unroll
        for (int k = 0; k < 2; ++k) {
            const f32x4 a = *(const f32x4*)&sQ[qq * 64 + k * 32 + g * 8];
            const f32x4 b = *(const f32x4*)&sQ[qq * 64 + k * 32 + g * 8 + 4];
            qs[k][0]=a[0]; qs[k][1]=a[1]; qs[k][2]=a[2]; qs[k][3]=a[3];
            qs[k][4]=b[0]; qs[k][5]=b[1]; qs[k][6]=b[2]; qs[k][7]=b[3];
        }
        short8 afrag[2][2];
        #pragma unroll
        for (int it = 0; it < 2; ++it) {
            const int row = w * 32 + it * 16 + sub;
            const int sw  = (row & 7) << 3;
            #pragma unroll
            for (int k = 0; k < 2; ++k) {
                const short8 kf = *(const short8*)&sK1[row * 64 + ((k * 32 + g * 8) ^ sw)];
                short8 af;
                #pragma unroll
                for (int e = 0; e < 8; ++e)
                    af[e] = (short)f2bf(bf2f(kf[e]) * qs[k][e]);
                afrag[it][k] = af;
            }
        }

        float pireg[2][4];
        float pjreg[16];
        #pragma unroll
        for (int a = 0; a < 2; ++a)
            #pragma unroll
            for (int b = 0; b < 4; ++b) pireg[a][b] = 0.f;
        #pragma unroll
        for (int a = 0; a < 16; ++a) pjreg[a] = 0.f;

        for (int c = 0; c < 4; ++c) {     // j-chunks of 64
            f32x4 acc[2][4];
            #pragma unroll
            for (int it = 0; it < 2; ++it)
                #pragma unroll
                for (int jt = 0; jt < 4; ++jt)
                    acc[it][jt] = (f32x4){0.f, 0.f, 0.f, 0.f};
            #pragma unroll
            for (int jt = 0; jt < 4; ++jt) {
                const int row = c * 64 + jt * 16 + sub;
                const int sw  = (row & 7) << 3;
                const short8 b0 = *(const short8*)&sK2[row * 64 + ((g * 8) ^ sw)];
                const short8 b1 = *(const short8*)&sK2[row * 64 + ((32 + g * 8) ^ sw)];
                #pragma unroll
                for (int it = 0; it < 2; ++it) {
                    acc[it][jt] = __builtin_amdgcn_mfma_f32_16x16x32_bf16(afrag[it][0], b0, acc[it][jt], 0, 0, 0);
                    acc[it][jt] = __builtin_amdgcn_mfma_f32_16x16x32_bf16(afrag[it][1], b1, acc[it][jt], 0, 0, 0);
                }
            }
            // epilogue: p = 2^t ; accumulate row (pi) and column (pj) sums
            #pragma unroll
            for (int it = 0; it < 2; ++it)
                #pragma unroll
                for (int jt = 0; jt < 4; ++jt)
                    #pragma unroll
                    for (int r = 0; r < 4; ++r) {
                        const float e = __builtin_amdgcn_exp2f(acc[it][jt][r]);
                        pireg[it][r]      += e;   // i = w*32 + it*16 + g*4 + r
                        pjreg[c * 4 + jt] += e;   // j = (c*4+jt)*16 + sub
                    }
        }

        // pi: reduce across the 16 lanes of each group (distinct j)
        #pragma unroll
        for (int it = 0; it < 2; ++it)
            #pragma unroll
            for (int r = 0; r < 4; ++r) {
                float v = pireg[it][r];
                v += __shfl_xor(v, 1); v += __shfl_xor(v, 2);
                v += __shfl_xor(v, 4); v += __shfl_xor(v, 8);
                if (sub == 0) sPi[qq][w * 32 + it * 16 + g * 4 + r] = v;
            }
        // pj: reduce across the 4 groups (distinct i), then across 8 waves
        float pjs[16];
        #pragma unroll
        for (int cj = 0; cj < 16; ++cj) {
            float v = pjreg[cj];
            v += __shfl_xor(v, 16); v += __shfl_xor(v, 32);
            pjs[cj] = v;
        }
        if (w < 4 && l < 16) {
            #pragma unroll
            for (int cj = 0; cj < 16; ++cj) sTmp[w][cj * 16 + l] = pjs[cj];
        }
        __syncthreads();
        if (w >= 4 && l < 16) {
            #pragma unroll
            for (int cj = 0; cj < 16; ++cj) sTmp[w - 4][cj * 16 + l] += pjs[cj];
        }
        __syncthreads();
        if (tid < 256)
            sPj[qq][tid] = sTmp[0][tid] + sTmp[1][tid] + sTmp[2][tid] + sTmp[3][tid];
        __syncthreads();
    }

    // ---- O partials: o[qq][d] = sum_i pi*V1 + sum_j pj*V2 (half-split) ----
    {
        const int qq = tid >> 7;          // 0..3
        const int hf = (tid >> 6) & 1;    // half of the i/j range
        const int d  = tid & 63;
        const float* V1h = v1g + h * (S_ * D_);
        const float* V2h = v2g + h * (S_ * D_);
        float a = 0.f;
        #pragma unroll 8
        for (int i = hf * 128; i < hf * 128 + 128; ++i) {
            a += sPi[qq][i] * V1h[i * D_ + d];
            a += sPj[qq][i] * V2h[i * D_ + d];
        }
        ((float*)sTmp)[hf * 256 + qq * 64 + d] = a;
    }
    __syncthreads();
    if (tid < 256) {
        const int qq = tid >> 6, d = tid & 63;
        float ls = sPi[qq][d] + sPi[qq][64 + d] + sPi[qq][128 + d] + sPi[qq][192 + d];
        ls += __shfl_xor(ls, 1);  ls += __shfl_xor(ls, 2);  ls += __shfl_xor(ls, 4);
        ls += __shfl_xor(ls, 8);  ls += __shfl_xor(ls, 16); ls += __shfl_xor(ls, 32);
        const float* sT = (const float*)sTmp;
        const float oo = sT[qq * 64 + d] + sT[256 + qq * 64 + d];
        outg[(h * S_ + q0 + qq) * D_ + d] = oo / ls;
        if (d == 0)
            outg[8 * S_ * D_ + h * S_ + q0 + qq] = logf(ls);
    }
}

extern "C" void kernel_launch(void* const* d_in, const int* in_sizes, int n_in,
                              void* d_out, int out_size, void* d_ws, size_t ws_size,
                              hipStream_t stream) {
    const float* q  = (const float*)d_in[0];
    const float* k1 = (const float*)d_in[1];
    const float* k2 = (const float*)d_in[2];
    const float* v1 = (const float*)d_in[3];
    const float* v2 = (const float*)d_in[4];
    float* out = (float*)d_out;
    tritt_fused<<<dim3(8 * (S_ / QB)), dim3(512), 0, stream>>>(q, k1, k2, v1, v2, out);
}

// Round 3
// 53.724 us; speedup vs baseline: 2.0997x; 2.0997x over previous
//
#include <hip/hip_runtime.h>
#include <hip/hip_bf16.h>

typedef __attribute__((ext_vector_type(8))) short short8;
typedef __attribute__((ext_vector_type(4))) float f32x4;

static constexpr int S_ = 256;
static constexpr int D_ = 64;
static constexpr int QB = 4;
// softmax scale * log2(e): GEMM directly produces log2-domain scores
static constexpr float QSCALE = 0.125f * 1.44269504088896340736f;

__device__ __forceinline__ float bf2f(short b) {
    union { unsigned int u; float f; } x;
    x.u = ((unsigned int)(unsigned short)b) << 16;
    return x.f;
}
__device__ __forceinline__ unsigned short f2bf(float f) {
    union { float f; unsigned int u; } x; x.f = f;
    unsigned int u = x.u + 0x7fffu + ((x.u >> 16) & 1u);   // RNE
    return (unsigned short)(u >> 16);
}

__global__ __launch_bounds__(512, 2) void tritt_fused(
    const float* __restrict__ qg, const float* __restrict__ k1g,
    const float* __restrict__ k2g, const float* __restrict__ v1g,
    const float* __restrict__ v2g, float* __restrict__ outg)
{
    __shared__ unsigned short sK1[S_ * D_];   // bf16, XOR-swizzled rows (32 KB)
    __shared__ unsigned short sK2[S_ * D_];   // 32 KB
    __shared__ float sQ[QB * D_];             // pre-scaled Q (1 KB)
    __shared__ float sPi[QB][S_];             // 4 KB
    __shared__ float sPj[QB][S_];             // 4 KB
    __shared__ float sTmp[4][S_];             // 4 KB: pj partials, then O partials

    const int tid = threadIdx.x;
    const int h  = blockIdx.x >> 6;
    const int q0 = (blockIdx.x & 63) * QB;

    const float* K1h = k1g + h * (S_ * D_);
    const float* K2h = k2g + h * (S_ * D_);

    // ---- stage K1,K2 as swizzled bf16 ----
    #pragma unroll
    for (int it = 0; it < 8; ++it) {
        const int e4  = tid * 4 + it * 2048;
        const int row = e4 >> 6, d = e4 & 63;
        const int idx = row * 64 + (d ^ ((row & 7) << 3));
        const float4 a = *(const float4*)(K1h + e4);
        sK1[idx]   = f2bf(a.x); sK1[idx+1] = f2bf(a.y);
        sK1[idx+2] = f2bf(a.z); sK1[idx+3] = f2bf(a.w);
        const float4 b = *(const float4*)(K2h + e4);
        sK2[idx]   = f2bf(b.x); sK2[idx+1] = f2bf(b.y);
        sK2[idx+2] = f2bf(b.z); sK2[idx+3] = f2bf(b.w);
    }
    if (tid < 256)
        sQ[tid] = qg[(h * S_ + q0 + (tid >> 6)) * D_ + (tid & 63)] * QSCALE;
    __syncthreads();

    const int w   = tid >> 6;   // wave id -> i-strip [w*32, w*32+32)
    const int l   = tid & 63;
    const int g   = l >> 4;     // 16-lane group (holds k-slice g*8..g*8+7)
    const int sub = l & 15;

    for (int qq = 0; qq < QB; ++qq) {
        // ---- A fragments: W[i,d] = K1[i,d] * Qs[d], bf16, in registers ----
        float qs[2][8];
        #pragma unroll
        for (int k = 0; k < 2; ++k) {
            const f32x4 a = *(const f32x4*)&sQ[qq * 64 + k * 32 + g * 8];
            const f32x4 b = *(const f32x4*)&sQ[qq * 64 + k * 32 + g * 8 + 4];
            qs[k][0]=a[0]; qs[k][1]=a[1]; qs[k][2]=a[2]; qs[k][3]=a[3];
            qs[k][4]=b[0]; qs[k][5]=b[1]; qs[k][6]=b[2]; qs[k][7]=b[3];
        }
        short8 afrag[2][2];
        #pragma unroll
        for (int it = 0; it < 2; ++it) {
            const int row = w * 32 + it * 16 + sub;
            const int sw  = (row & 7) << 3;
            #pragma unroll
            for (int k = 0; k < 2; ++k) {
                const short8 kf = *(const short8*)&sK1[row * 64 + ((k * 32 + g * 8) ^ sw)];
                short8 af;
                #pragma unroll
                for (int e = 0; e < 8; ++e)
                    af[e] = (short)f2bf(bf2f(kf[e]) * qs[k][e]);
                afrag[it][k] = af;
            }
        }

        float pireg[2][4];
        float pjreg[16];
        #pragma unroll
        for (int a = 0; a < 2; ++a)
            #pragma unroll
            for (int b = 0; b < 4; ++b) pireg[a][b] = 0.f;
        #pragma unroll
        for (int a = 0; a < 16; ++a) pjreg[a] = 0.f;

        #pragma unroll
        for (int c = 0; c < 4; ++c) {     // j-chunks of 64 (UNROLLED: static pjreg idx)
            f32x4 acc[2][4];
            #pragma unroll
            for (int it = 0; it < 2; ++it)
                #pragma unroll
                for (int jt = 0; jt < 4; ++jt)
                    acc[it][jt] = (f32x4){0.f, 0.f, 0.f, 0.f};
            #pragma unroll
            for (int jt = 0; jt < 4; ++jt) {
                const int row = c * 64 + jt * 16 + sub;
                const int sw  = (row & 7) << 3;
                const short8 b0 = *(const short8*)&sK2[row * 64 + ((g * 8) ^ sw)];
                const short8 b1 = *(const short8*)&sK2[row * 64 + ((32 + g * 8) ^ sw)];
                #pragma unroll
                for (int it = 0; it < 2; ++it) {
                    acc[it][jt] = __builtin_amdgcn_mfma_f32_16x16x32_bf16(afrag[it][0], b0, acc[it][jt], 0, 0, 0);
                    acc[it][jt] = __builtin_amdgcn_mfma_f32_16x16x32_bf16(afrag[it][1], b1, acc[it][jt], 0, 0, 0);
                }
            }
            // epilogue: p = 2^t ; accumulate row (pi) and column (pj) sums
            #pragma unroll
            for (int it = 0; it < 2; ++it)
                #pragma unroll
                for (int jt = 0; jt < 4; ++jt)
                    #pragma unroll
                    for (int r = 0; r < 4; ++r) {
                        const float e = __builtin_amdgcn_exp2f(acc[it][jt][r]);
                        pireg[it][r]      += e;   // i = w*32 + it*16 + g*4 + r
                        pjreg[c * 4 + jt] += e;   // j = (c*4+jt)*16 + sub
                    }
        }

        // pi: reduce across the 16 lanes of each group (distinct j)
        #pragma unroll
        for (int it = 0; it < 2; ++it)
            #pragma unroll
            for (int r = 0; r < 4; ++r) {
                float v = pireg[it][r];
                v += __shfl_xor(v, 1); v += __shfl_xor(v, 2);
                v += __shfl_xor(v, 4); v += __shfl_xor(v, 8);
                if (sub == 0) sPi[qq][w * 32 + it * 16 + g * 4 + r] = v;
            }
        // pj: reduce across the 4 groups (distinct i), then across 8 waves
        float pjs[16];
        #pragma unroll
        for (int cj = 0; cj < 16; ++cj) {
            float v = pjreg[cj];
            v += __shfl_xor(v, 16); v += __shfl_xor(v, 32);
            pjs[cj] = v;
        }
        if (w < 4 && l < 16) {
            #pragma unroll
            for (int cj = 0; cj < 16; ++cj) sTmp[w][cj * 16 + l] = pjs[cj];
        }
        __syncthreads();
        if (w >= 4 && l < 16) {
            #pragma unroll
            for (int cj = 0; cj < 16; ++cj) sTmp[w - 4][cj * 16 + l] += pjs[cj];
        }
        __syncthreads();
        if (tid < 256)
            sPj[qq][tid] = sTmp[0][tid] + sTmp[1][tid] + sTmp[2][tid] + sTmp[3][tid];
        __syncthreads();
    }

    // ---- O partials: o[qq][d] = sum_i pi*V1 + sum_j pj*V2 (half-split) ----
    {
        const int qq = tid >> 7;          // 0..3
        const int hf = (tid >> 6) & 1;    // half of the i/j range
        const int d  = tid & 63;
        const float* V1h = v1g + h * (S_ * D_);
        const float* V2h = v2g + h * (S_ * D_);
        float a = 0.f;
        #pragma unroll 8
        for (int i = hf * 128; i < hf * 128 + 128; ++i) {
            a += sPi[qq][i] * V1h[i * D_ + d];
            a += sPj[qq][i] * V2h[i * D_ + d];
        }
        ((float*)sTmp)[hf * 256 + qq * 64 + d] = a;
    }
    __syncthreads();
    if (tid < 256) {
        const int qq = tid >> 6, d = tid & 63;
        float ls = sPi[qq][d] + sPi[qq][64 + d] + sPi[qq][128 + d] + sPi[qq][192 + d];
        ls += __shfl_xor(ls, 1);  ls += __shfl_xor(ls, 2);  ls += __shfl_xor(ls, 4);
        ls += __shfl_xor(ls, 8);  ls += __shfl_xor(ls, 16); ls += __shfl_xor(ls, 32);
        const float* sT = (const float*)sTmp;
        const float oo = sT[qq * 64 + d] + sT[256 + qq * 64 + d];
        outg[(h * S_ + q0 + qq) * D_ + d] = oo / ls;
        if (d == 0)
            outg[8 * S_ * D_ + h * S_ + q0 + qq] = logf(ls);
    }
}

extern "C" void kernel_launch(void* const* d_in, const int* in_sizes, int n_in,
                              void* d_out, int out_size, void* d_ws, size_t ws_size,
                              hipStream_t stream) {
    const float* q  = (const float*)d_in[0];
    const float* k1 = (const float*)d_in[1];
    const float* k2 = (const float*)d_in[2];
    const float* v1 = (const float*)d_in[3];
    const float* v2 = (const float*)d_in[4];
    float* out = (float*)d_out;
    tritt_fused<<<dim3(8 * (S_ / QB)), dim3(512), 0, stream>>>(q, k1, k2, v1, v2, out);
}

// Round 4
// 46.396 us; speedup vs baseline: 2.4313x; 1.1579x over previous
//
#include <hip/hip_runtime.h>
#include <hip/hip_bf16.h>

typedef __attribute__((ext_vector_type(8))) short short8;
typedef __attribute__((ext_vector_type(4))) float f32x4;

static constexpr int S_ = 256;
static constexpr int D_ = 64;
static constexpr int QB = 4;
// softmax scale * log2(e): GEMM directly produces log2-domain scores
static constexpr float QSCALE = 0.125f * 1.44269504088896340736f;

__device__ __forceinline__ float bf2f(short b) {
    union { unsigned int u; float f; } x;
    x.u = ((unsigned int)(unsigned short)b) << 16;
    return x.f;
}
// one-instruction RNE pack of two f32 -> packed bf16x2
__device__ __forceinline__ unsigned cvt_pk_bf16(float lo, float hi) {
    unsigned r;
    asm("v_cvt_pk_bf16_f32 %0, %1, %2" : "=v"(r) : "v"(lo), "v"(hi));
    return r;
}

__global__ __launch_bounds__(256, 2) void tritt_fused(
    const float* __restrict__ qg, const float* __restrict__ k1g,
    const float* __restrict__ k2g, const float* __restrict__ v1g,
    const float* __restrict__ v2g, float* __restrict__ outg)
{
    __shared__ unsigned short sK1[S_ * D_];   // bf16, XOR-swizzled rows (32 KB)
    __shared__ unsigned short sK2[S_ * D_];   // 32 KB
    __shared__ float sQ[QB * D_];             // pre-scaled Q
    __shared__ float sPi[QB][S_];             // per-wave strips (wave-local!)
    __shared__ float sPj[QB][S_];

    const int tid = threadIdx.x;
    const int h  = blockIdx.x >> 6;
    const int q0 = (blockIdx.x & 63) * QB;

    const float* K1h = k1g + h * (S_ * D_);
    const float* K2h = k2g + h * (S_ * D_);

    // ---- stage K1,K2 as swizzled bf16 (cvt_pk: 2 f32 -> 1 inst) ----
    #pragma unroll
    for (int it = 0; it < 16; ++it) {
        const int e4  = tid * 4 + it * 1024;
        const int row = e4 >> 6, d = e4 & 63;
        const int idx = row * 64 + (d ^ ((row & 7) << 3));  // low 3 bits of d intact
        const float4 a = *(const float4*)(K1h + e4);
        uint2 pa; pa.x = cvt_pk_bf16(a.x, a.y); pa.y = cvt_pk_bf16(a.z, a.w);
        *(uint2*)&sK1[idx] = pa;
        const float4 b = *(const float4*)(K2h + e4);
        uint2 pb; pb.x = cvt_pk_bf16(b.x, b.y); pb.y = cvt_pk_bf16(b.z, b.w);
        *(uint2*)&sK2[idx] = pb;
    }
    sQ[tid] = qg[(h * S_ + q0 + (tid >> 6)) * D_ + (tid & 63)] * QSCALE;
    __syncthreads();   // the ONLY block-wide barrier

    const int w   = tid >> 6;   // wave id == query index within tile
    const int l   = tid & 63;
    const int g   = l >> 4;     // 16-lane group (k-slice g*8..g*8+7)
    const int sub = l & 15;

    // Q fragment for this wave's query (lives whole kernel)
    float qs[2][8];
    #pragma unroll
    for (int k = 0; k < 2; ++k) {
        const f32x4 a = *(const f32x4*)&sQ[w * 64 + k * 32 + g * 8];
        const f32x4 b = *(const f32x4*)&sQ[w * 64 + k * 32 + g * 8 + 4];
        qs[k][0]=a[0]; qs[k][1]=a[1]; qs[k][2]=a[2]; qs[k][3]=a[3];
        qs[k][4]=b[0]; qs[k][5]=b[1]; qs[k][6]=b[2]; qs[k][7]=b[3];
    }

    float pjreg[16];
    #pragma unroll
    for (int a = 0; a < 16; ++a) pjreg[a] = 0.f;

    // ---- sweep all 16 i-tiles x full j range, barrier-free ----
    #pragma unroll 2
    for (int it = 0; it < 16; ++it) {
        // A fragment: W[i,d] = K1[i,d] * Qs[d], packed bf16
        const int arow = it * 16 + sub;
        const int asw  = (arow & 7) << 3;
        short8 af[2];
        #pragma unroll
        for (int k = 0; k < 2; ++k) {
            const short8 kf = *(const short8*)&sK1[arow * 64 + ((k * 32 + g * 8) ^ asw)];
            unsigned p0 = cvt_pk_bf16(bf2f(kf[0]) * qs[k][0], bf2f(kf[1]) * qs[k][1]);
            unsigned p1 = cvt_pk_bf16(bf2f(kf[2]) * qs[k][2], bf2f(kf[3]) * qs[k][3]);
            unsigned p2 = cvt_pk_bf16(bf2f(kf[4]) * qs[k][4], bf2f(kf[5]) * qs[k][5]);
            unsigned p3 = cvt_pk_bf16(bf2f(kf[6]) * qs[k][6], bf2f(kf[7]) * qs[k][7]);
            union { unsigned u[4]; short8 s; } pk;
            pk.u[0] = p0; pk.u[1] = p1; pk.u[2] = p2; pk.u[3] = p3;
            af[k] = pk.s;
        }

        float pireg[4] = {0.f, 0.f, 0.f, 0.f};

        #pragma unroll
        for (int jc = 0; jc < 4; ++jc) {       // j-chunks of 64
            f32x4 acc[4];
            #pragma unroll
            for (int jt = 0; jt < 4; ++jt) acc[jt] = (f32x4){0.f, 0.f, 0.f, 0.f};
            #pragma unroll
            for (int jt = 0; jt < 4; ++jt) {
                const int jrow = jc * 64 + jt * 16 + sub;
                const int jsw  = (jrow & 7) << 3;
                const short8 b0 = *(const short8*)&sK2[jrow * 64 + ((g * 8) ^ jsw)];
                const short8 b1 = *(const short8*)&sK2[jrow * 64 + ((32 + g * 8) ^ jsw)];
                acc[jt] = __builtin_amdgcn_mfma_f32_16x16x32_bf16(af[0], b0, acc[jt], 0, 0, 0);
                acc[jt] = __builtin_amdgcn_mfma_f32_16x16x32_bf16(af[1], b1, acc[jt], 0, 0, 0);
            }
            // p = 2^t ; accumulate row (pi) and column (pj) sums
            #pragma unroll
            for (int jt = 0; jt < 4; ++jt)
                #pragma unroll
                for (int r = 0; r < 4; ++r) {
                    const float e = __builtin_amdgcn_exp2f(acc[jt][r]);
                    pireg[r]           += e;   // i = it*16 + g*4 + r
                    pjreg[jc * 4 + jt] += e;   // j = (jc*4+jt)*16 + sub
                }
        }

        // pi reduce over the 16 sub lanes (distinct j) -> wave-local strip
        #pragma unroll
        for (int r = 0; r < 4; ++r) {
            float v = pireg[r];
            v += __shfl_xor(v, 1); v += __shfl_xor(v, 2);
            v += __shfl_xor(v, 4); v += __shfl_xor(v, 8);
            if (sub == 0) sPi[w][it * 16 + g * 4 + r] = v;
        }
    }

    // pj reduce over the 4 groups (distinct i) -> wave-local strip
    #pragma unroll
    for (int jt = 0; jt < 16; ++jt) {
        float v = pjreg[jt];
        v += __shfl_xor(v, 16); v += __shfl_xor(v, 32);
        if (l < 16) sPj[w][jt * 16 + l] = v;
    }

    // ---- per-wave epilogue: l = sum pi ; o[d] = sum pi*V1 + sum pj*V2 ----
    float ls = sPi[w][l] + sPi[w][64 + l] + sPi[w][128 + l] + sPi[w][192 + l];
    ls += __shfl_xor(ls, 1);  ls += __shfl_xor(ls, 2);  ls += __shfl_xor(ls, 4);
    ls += __shfl_xor(ls, 8);  ls += __shfl_xor(ls, 16); ls += __shfl_xor(ls, 32);

    const float* V1h = v1g + h * (S_ * D_);
    const float* V2h = v2g + h * (S_ * D_);
    float o = 0.f;
    #pragma unroll 4
    for (int ib = 0; ib < 32; ++ib) {
        const f32x4 a0 = *(const f32x4*)&sPi[w][ib * 8];
        const f32x4 a1 = *(const f32x4*)&sPi[w][ib * 8 + 4];
        const f32x4 b0 = *(const f32x4*)&sPj[w][ib * 8];
        const f32x4 b1 = *(const f32x4*)&sPj[w][ib * 8 + 4];
        #pragma unroll
        for (int e = 0; e < 4; ++e) {
            o += a0[e] * V1h[(ib * 8 + e) * D_ + l]     + b0[e] * V2h[(ib * 8 + e) * D_ + l];
            o += a1[e] * V1h[(ib * 8 + 4 + e) * D_ + l] + b1[e] * V2h[(ib * 8 + 4 + e) * D_ + l];
        }
    }
    outg[(h * S_ + q0 + w) * D_ + l] = o / ls;
    if (l == 0)
        outg[8 * S_ * D_ + h * S_ + q0 + w] = logf(ls);
}

extern "C" void kernel_launch(void* const* d_in, const int* in_sizes, int n_in,
                              void* d_out, int out_size, void* d_ws, size_t ws_size,
                              hipStream_t stream) {
    const float* q  = (const float*)d_in[0];
    const float* k1 = (const float*)d_in[1];
    const float* k2 = (const float*)d_in[2];
    const float* v1 = (const float*)d_in[3];
    const float* v2 = (const float*)d_in[4];
    float* out = (float*)d_out;
    tritt_fused<<<dim3(8 * (S_ / QB)), dim3(256), 0, stream>>>(q, k1, k2, v1, v2, out);
}